// Round 16
// baseline (1302.635 us; speedup 1.0000x reference)
//
#include <hip/hip_runtime.h>
#include <cstdint>
#include <cstddef>

// Problem constants
#define N_NEU   4096
#define N_IN    1024
#define B_SZ    8
#define T_STEPS 500
#define NSLICE  16
#define NBLK    (B_SZ * NSLICE)     // 128 blocks; 512 thr (4 sim + 4 helper waves)
#define FF_WORDS (B_SZ * T_STEPS * 16)
#define FFP_CAP 128                 // per-tb list cap (mean actives ~51)
#define N_PAIRS (B_SZ * T_STEPS)    // 4000 (t,b) pairs

// ws layout:
//   [0)        u64 tmask[64]            512 B
//   [512)      u64 mb2[2][8][64][2]     16 KB  (tagged dbuf spike words)
//   [17408)    u64 ffmask[B*T*16]       512 KB (input-spike bitmasks)
//   [529408)   float ffdrive[T][B][N]   65.5 MB (FF drive)
//   [66065408) int fflist_n[4000]       16 KB  (true counts)
//   [66081792) int fflist[4000][128]    2 MB   (shared padded lists)
#define WS_TM_OFF    0
#define WS_MB_OFF    512
#define WS_FFM_OFF   17408
#define WS_FFD_OFF   529408
#define WS_FLN_OFF   66065408
#define WS_FL_OFF    66081792
#define WS_NEED_FFD  (529408 + (size_t)T_STEPS * B_SZ * N_NEU * 4)   // ffdrive only
#define WS_NEED_FL   (66081792 + (size_t)N_PAIRS * FFP_CAP * 4)      // + lists

__global__ __launch_bounds__(64) void snn_init(const int* __restrict__ ci,
                                               unsigned long long* __restrict__ tmask,
                                               unsigned long long* __restrict__ mb2) {
    const int k = blockIdx.x, l = threadIdx.x;   // 64 blocks x 64 threads
    unsigned long long m = __ballot(ci[(k << 6) + l] == 0);
    if (l == 0) tmask[k] = m;
    const int idx = (k << 6) + l;
    if (idx < 2048) mb2[idx] = 0ULL;             // tag 0 never matches t>=1
}

// input spikes (B,T,NI) -> bitmask words, 64 elems per word, ascending order
__global__ __launch_bounds__(256) void snn_ffmask(const float* __restrict__ inspk,
                                                  unsigned long long* __restrict__ ffmask) {
    int gid = blockIdx.x * 256 + threadIdx.x;
    int wid = gid >> 6, lane = gid & 63;
    int nw  = (gridDim.x * 256) >> 6;
    for (int w = wid; w < FF_WORDS; w += nw) {
        float v = inspk[(size_t)w * 64 + lane];
        unsigned long long m = __ballot(v > 0.5f);
        if (lane == 0) ffmask[w] = m;
    }
}

// Extract set-bit indices of a distributed 64x64-bit mask into lds as typed
// entries (idx<<2)|ty, globally ascending. Pads to a multiple of 64 with
// sentinels (ty 2). Returns real count.
__device__ __forceinline__ int extract_pad(unsigned long long m,
                                           unsigned long long tm_exc,
                                           int* lds, int lane) {
    int pc  = __popcll(m);
    int sum = pc;
#pragma unroll
    for (int d = 1; d < 64; d <<= 1) {
        int o = __shfl_up(sum, d, 64);
        if (lane >= d) sum += o;
    }
    int off   = sum - pc;           // exclusive prefix
    int total = __shfl(sum, 63, 64);
    int base  = lane << 6;
    while (m) {
        int bit = __builtin_ctzll(m);
        int ty  = ((tm_exc >> bit) & 1ULL) ? 0 : 1;
        lds[off++] = ((base + bit) << 2) | ty;
        m &= m - 1ULL;
    }
    int padcnt = (-total) & 63;
    if (lane < padcnt) lds[total + lane] = 2;   // sentinel: idx 0, ty 2
    return total;
}

// Capped extract (all ty0) with write guard — safe into a 128-slot buffer.
__device__ __forceinline__ int extract_cap(unsigned long long m,
                                           int* buf, int lane) {
    int pc  = __popcll(m);
    int sum = pc;
#pragma unroll
    for (int d = 1; d < 64; d <<= 1) {
        int o = __shfl_up(sum, d, 64);
        if (lane >= d) sum += o;
    }
    int off   = sum - pc;
    int total = __shfl(sum, 63, 64);
    int base  = lane << 6;
    while (m) {
        int bit = __builtin_ctzll(m);
        if (off < FFP_CAP) buf[off] = (base + bit) << 2;   // ty0
        ++off;
        m &= m - 1ULL;
    }
    if (total < FFP_CAP) {
        int padcnt = (-total) & 63;
        if (lane < padcnt && total + lane < FFP_CAP)
            buf[total + lane] = 2;                         // sentinel ty2
    }
    return total;
}

// Build the 4000 shared FF lists ONCE (R11 lesson: per-block re-extraction
// was the dominant ffpre cost).
__global__ __launch_bounds__(256) void snn_fflist(
    const unsigned long long* __restrict__ ffmask,
    int* __restrict__ fflist,
    int* __restrict__ fflist_n)
{
    const int lane = threadIdx.x & 63;
    const int wv   = threadIdx.x >> 6;
    const int w    = blockIdx.x * 4 + wv;      // 250 blocks x 4 waves = 1000
    for (int q = 0; q < 4; ++q) {
        const int p = w * 4 + q;               // pair index = t*8 + b
        const int t = p >> 3, b = p & 7;
        const unsigned long long mf =
            (lane < 16) ? ffmask[((size_t)b * T_STEPS + t) * 16 + lane] : 0ULL;
        const int n = extract_cap(mf, fflist + (size_t)p * FFP_CAP, lane);
        if (lane == 0) fflist_n[p] = n;
    }
}

// Combined typed gather (recurrent): proven pipelined structure. Unchanged.
__device__ __forceinline__ void gather2(const int* __restrict__ lst, int npad,
                                        const float* __restrict__ base,
                                        float se, float si,
                                        float* oe, float* oi) {
#pragma clang fp contract(off)
    float ae = 0.0f, ai = 0.0f;
    const int4* lst4 = (const int4*)lst;
    for (int k = 0; k < npad; k += 64) {
        int4  eq[16];
        int   e[64];
        float w[64];
#pragma unroll
        for (int u = 0; u < 16; ++u) eq[u] = lst4[(k >> 2) + u];
#pragma unroll
        for (int u = 0; u < 16; ++u) {
            e[4 * u + 0] = eq[u].x; e[4 * u + 1] = eq[u].y;
            e[4 * u + 2] = eq[u].z; e[4 * u + 3] = eq[u].w;
        }
#pragma unroll
        for (int u = 0; u < 64; ++u) w[u] = base[(size_t)(e[u] >> 2) << 12];
#pragma unroll
        for (int u = 0; u < 64; ++u) {
            const int ty = e[u] & 3;
            const float sc = (ty == 0) ? se : ((ty == 1) ? si : 0.0f);
            const float p  = w[u] * sc;           // per-element product rounding = W_eff
            ae = (ty == 0) ? ae + p : ae;
            ai = (ty == 1) ? ai + p : ai;
        }
    }
    *oe = ae; *oi = ai;
}

// Old FF precompute (R6-proven, ~425us LLC-bound): workspace fallback only.
__global__ __launch_bounds__(64) void snn_ffpre(const unsigned long long* __restrict__ ffmask,
                                                const float* __restrict__ Wff,
                                                const float* __restrict__ sfff,
                                                const int*   __restrict__ ci,
                                                float*       __restrict__ ffdrive) {
#pragma clang fp contract(off)
    const int lane  = threadIdx.x;
    const int chunk = blockIdx.x & 63;
    const int tile  = blockIdx.x >> 6;     // 160 tiles of 25 (t,b) pairs
    const int i     = (chunk << 6) + lane;
    const float s_ff = sfff[ci[i]];
    __shared__ alignas(16) int lds_f[N_IN + 64];
    for (int p = tile * 25; p < tile * 25 + 25; ++p) {
        const int t = p >> 3, b = p & 7;
        const unsigned long long mf =
            (lane < 16) ? ffmask[((size_t)b * T_STEPS + t) * 16 + lane] : 0ULL;
        const int n = extract_pad(mf, ~0ULL, lds_f, lane);   // all ty0
        float fd, dummy;
        gather2(lds_f, (n + 63) & ~63, Wff + i, s_ff, 0.0f, &fd, &dummy);
        ffdrive[((size_t)t * B_SZ + b) * N_NEU + i] = fd;
    }
}

// snn_run: 512 threads. Pre-phase (all 8 waves): fill THIS BLOCK'S
// ffdrive[*, b, slice-cols] using an LDS-STAGED Wff tile (the R14 fusion
// failed because it folded from GLOBAL Wff — L2-latency chains; staging was
// the proven ffpre2-5 lever). lds_c (unused until the time loop) aliases as
// a 1024x16 float tile; 16 column-chunks; 32 t-streams x 16 cols fold from
// the shared fflist (uniform broadcast loads). Same-block produce ->
// __syncthreads -> consume (same CU, coherent; no cross-XCD transport).
// Then helpers return; waves 0-3 run the byte-identical R6 sim loop.
__global__ __launch_bounds__(512) void snn_run(
    const float* __restrict__ W,       // (N,N) row j = presyn
    const float* __restrict__ Wff,     // (NI,N)
    const float* __restrict__ sf,      // (2,2)
    const float* __restrict__ sfff,    // (1,2)
    const int*   __restrict__ ci,      // (N)
    float*       __restrict__ out,     // (B,T,N)
    const unsigned long long* __restrict__ ffmask,
    const unsigned long long* __restrict__ tmask_g,
    float*       __restrict__ ffdrive,
    const int*   __restrict__ fflist,
    const int*   __restrict__ fflist_n,
    int use_ffpre,   // ffdrive valid for the sim loop
    int use_fl,      // fflist valid -> run the fused staged pre-phase
    unsigned long long* __restrict__ mb2)
{
#pragma clang fp contract(off)
    const int tid   = threadIdx.x;
    const int lane  = tid & 63;
    const int wv    = tid >> 6;          // 0..7
    const int bid   = blockIdx.x;
    // slice from bits {0,1,2,6}, batch from bits {3,4,5}
    const int slice = (((bid >> 6) & 1) << 3) | (bid & 7);
    const int b     = (bid >> 3) & 7;

    // Per-wave private LDS regions (sim): NO cross-wave sharing -> no barriers
    // in the time loop. During the pre-phase, lds_c aliases as the Wff tile.
    __shared__ alignas(16) int lds_c[4][N_NEU + 64];
    __shared__ alignas(16) int lds_f[4][N_IN + 64];

    // ---- fused FF pre-phase (all 8 waves), staged-LDS fold ----
    if (use_fl) {
        float* tile = (float*)lds_c;            // 1024 x 16 floats = 64 KB
        const int j16  = tid & 15;              // col within chunk
        const int strm = tid >> 4;              // 0..31 t-streams
        for (int ch = 0; ch < 16; ++ch) {
            const int col0 = (slice << 8) + (ch << 4);
            // stage Wff[:, col0..col0+15]: 32 rows in parallel, 64B/row
            for (int r = strm; r < N_IN; r += 32)
                tile[r * 16 + j16] = Wff[(size_t)r * N_NEU + col0 + j16];
            __syncthreads();
            const int jg = col0 + j16;
            const float psff = sfff[ci[jg]];
            for (int t = strm; t < T_STEPS; t += 32) {
                const int p  = (t << 3) | b;    // pair index = t*8 + b
                const int nf = fflist_n[p];
                float acc = 0.0f;
                if (nf <= FFP_CAP) {
                    // 16-entry chunks; reads <= roundup64(nf) entries, all
                    // initialized (extract_cap pads to a 64-multiple).
                    const int4* l4 = (const int4*)(fflist + (size_t)p * FFP_CAP);
                    const int nch = (nf + 15) >> 4;
                    for (int cc = 0; cc < nch; ++cc) {
                        int4 eq[4];
#pragma unroll
                        for (int u = 0; u < 4; ++u) eq[u] = l4[cc * 4 + u];
                        int e[16];
#pragma unroll
                        for (int u = 0; u < 4; ++u) {
                            e[4 * u + 0] = eq[u].x; e[4 * u + 1] = eq[u].y;
                            e[4 * u + 2] = eq[u].z; e[4 * u + 3] = eq[u].w;
                        }
                        float w[16];
#pragma unroll
                        for (int u = 0; u < 16; ++u)
                            w[u] = tile[(e[u] >> 2) * 16 + j16];
#pragma unroll
                        for (int u = 0; u < 16; ++u) {
                            const float sc = ((e[u] & 3) == 0) ? psff : 0.0f;
                            const float pr = w[u] * sc;
                            acc += pr;          // ascending-i left fold
                        }
                    }
                } else {
                    // exact slow path (P~1e-18): ascending bit-walk over mask
                    const unsigned long long* mp =
                        ffmask + ((size_t)b * T_STEPS + t) * 16;
                    for (int w16 = 0; w16 < 16; ++w16) {
                        unsigned long long mw = mp[w16];
                        const int base = w16 << 6;
                        while (mw) {
                            const int bit = __builtin_ctzll(mw); mw &= mw - 1ULL;
                            const float pr = tile[(base + bit) * 16 + j16] * psff;
                            acc += pr;
                        }
                    }
                }
                ffdrive[(size_t)p * N_NEU + jg] = acc;
            }
            __syncthreads();   // before next chunk's staging overwrites tile
        }
    }
    __syncthreads();      // pre-phase stores ordered before sim-phase reads
    if (wv >= 4) return;  // helpers done; sim loop below has NO barriers

    // ---- sim role: byte-identical R6 loop ----
    const int i = (slice << 8) + (wv << 6) + lane;    // my post neuron
    const int c = ci[i];

    const float s_exc = sf[c];
    const float s_inh = sf[2 + c];
    const float s_ff  = sfff[c];

    const unsigned long long my_tm = tmask_g[lane];
    int* const my_ldsc = lds_c[wv];
    int* const my_ldsf = lds_f[wv];

    // mb2 layout (u64 units): [parity][batch][entry=(slice<<2)|wv][half]
    unsigned long long* const mbB = mb2 + (size_t)b * 128;

    float v = -70.0f, rf = 0.0f;
    float h0 = 0.0f, h1 = 0.0f, h2 = 0.0f, h3 = 0.0f;
    float g0 = 0.0f, g1 = 0.0f, g2 = 0.0f, g3 = 0.0f;

    const float aR0 = expf(-0.1f / 0.5f);
    const float aR1 = expf(-0.1f / 2.0f);
    const float aD0 = expf(-0.1f / 2.0f);
    const float aD1 = expf(-0.1f / 100.0f);
    const float aD2 = expf(-0.1f / 5.0f);
    const float kmem   = c ? (0.1f / 10.0f) : (0.1f / 20.0f);
    const float rsteps = c ? 10.0f : 20.0f;

    // warming base: this wave's 256B segment start within any W row
    const float* const wseg = W + (size_t)((slice << 8) + (wv << 6));

    for (int t = 0; t < T_STEPS; ++t) {
        // ffdrive issued BEFORE the poll: its latency hides under detection.
        float ffd = 0.0f;
        if (use_ffpre) {
            ffd = ffdrive[((size_t)t * B_SZ + b) * N_NEU + i];
            asm volatile("" :: "v"(ffd));
        }

        unsigned long long mw = 0ULL;
        if (t > 0) {
            // tagged single-hop poll: lane l owns entry l; parity dbuf; no
            // ABA (publish(t+2) requires every block past poll(t)).
            const unsigned int tg = (unsigned int)t;
            const unsigned long long* ep =
                mbB + (size_t)(t & 1) * 1024 + ((size_t)lane << 1);
            unsigned long long w0, w1;
            for (;;) {
                w0 = __hip_atomic_load(&ep[0], __ATOMIC_RELAXED,
                                       __HIP_MEMORY_SCOPE_AGENT);
                w1 = __hip_atomic_load(&ep[1], __ATOMIC_RELAXED,
                                       __HIP_MEMORY_SCOPE_AGENT);
                const bool ok = ((unsigned int)(w0 >> 32) == tg) &&
                                ((unsigned int)(w1 >> 32) == tg);
                if (__ballot(ok) == ~0ULL) break;
                __builtin_amdgcn_s_sleep(1);
            }
            mw = (w0 & 0xFFFFFFFFULL) | ((w1 & 0xFFFFFFFFULL) << 32);
            asm volatile("" ::: "memory");   // keep LDS writes below poll
        }

        // ---- line warming: pull this step's W row-segments toward L1 while
        // the extract scan runs; real gather loads MSHR-merge.
        {
            unsigned long long mm = mw;
            float wacc = 0.0f;
            const size_t rowbase = (size_t)lane << 18;  // (lane*64)<<12 floats
            while (mm) {
                const int bit = __builtin_ctzll(mm); mm &= mm - 1ULL;
                const float* r = wseg + rowbase + ((size_t)bit << 12);
                wacc += r[0]; wacc += r[16]; wacc += r[32]; wacc += r[48];
            }
            asm volatile("" :: "v"(wacc));
        }

        // zero-skip: fully-silent network step -> no extract scan needed.
        int ne = 0;
        if (__ballot(mw != 0ULL) != 0ULL)
            ne = extract_pad(mw, my_tm, my_ldsc, lane);

        if (!use_ffpre) {
            const unsigned long long mf =
                (lane < 16) ? ffmask[((size_t)b * T_STEPS + t) * 16 + lane] : 0ULL;
            const int nf = extract_pad(mf, ~0ULL, my_ldsf, lane);
            float fd, dummy;
            gather2(my_ldsf, (nf + 63) & ~63, Wff + i, s_ff, 0.0f, &fd, &dummy);
            ffd = fd;
        }

        float exc, inh;
        gather2(my_ldsc, (ne + 63) & ~63, W + i, s_exc, s_inh, &exc, &inh);

        // ---- neuron update (identical fp op sequence to R0-R15: bit-exact) ----
        const float d0 = exc;
        const float d1 = 0.5f * exc;
        const float d2 = inh;
        const float d3 = ffd;

        h0 = fmaf(h0, aR0, d0);
        h1 = fmaf(h1, aR1, d1);
        h2 = fmaf(h2, aR0, d2);
        h3 = fmaf(h3, aR0, d3);
        g0 = fmaf(g0, aD0, (1.0f - aD0) * h0);
        g1 = fmaf(g1, aD1, (1.0f - aD1) * h1);
        g2 = fmaf(g2, aD2, (1.0f - aD2) * h2);
        g3 = fmaf(g3, aD0, (1.0f - aD0) * h3);

        const float p0 = g0 * (0.0f - v);
        const float p1 = g1 * (0.0f - v);
        const float p2 = g2 * (-80.0f - v);
        const float p3 = g3 * (0.0f - v);
        const float Isyn = ((p0 + p1) + p2) + p3;

        float vn = fmaf(kmem, (-70.0f - v) + Isyn / 10.0f, v);
        const bool refr = rf > 0.0f;
        if (refr) vn = -65.0f;
        const float sn = (!refr && (vn > -50.0f)) ? 1.0f : 0.0f;
        const bool spk = sn > 0.5f;

        // publish at the EARLIEST instant: right after the spike decision.
        const unsigned long long sm = __ballot(spk);
        if (lane == 0) {
            const unsigned long long tg =
                (unsigned long long)(unsigned int)(t + 1) << 32;
            unsigned long long* pp = mb2 + (size_t)((t + 1) & 1) * 1024
                                   + (size_t)b * 128
                                   + ((size_t)((slice << 2) | wv) << 1);
            __hip_atomic_store(&pp[0], tg | (sm & 0xFFFFFFFFULL),
                               __ATOMIC_RELAXED, __HIP_MEMORY_SCOPE_AGENT);
            __hip_atomic_store(&pp[1], tg | (sm >> 32),
                               __ATOMIC_RELAXED, __HIP_MEMORY_SCOPE_AGENT);
        }

        v  = spk ? -65.0f : vn;
        rf = spk ? rsteps : fmaxf(rf - 1.0f, 0.0f);
        out[((size_t)b * T_STEPS + t) * N_NEU + i] = sn;   // regular store
    }
}

extern "C" void kernel_launch(void* const* d_in, const int* in_sizes, int n_in,
                              void* d_out, int out_size, void* d_ws, size_t ws_size,
                              hipStream_t stream) {
    const float* inspk = (const float*)d_in[0];
    const float* W     = (const float*)d_in[1];
    const float* Wff   = (const float*)d_in[2];
    const float* sf    = (const float*)d_in[3];
    const float* sfff  = (const float*)d_in[4];
    const int*   ci    = (const int*)d_in[5];

    float* out = (float*)d_out;
    unsigned long long* tmask    = (unsigned long long*)((char*)d_ws + WS_TM_OFF);
    unsigned long long* mb2      = (unsigned long long*)((char*)d_ws + WS_MB_OFF);
    unsigned long long* ffmask   = (unsigned long long*)((char*)d_ws + WS_FFM_OFF);
    float*              ffdrive  = (float*)((char*)d_ws + WS_FFD_OFF);
    int*                fflist_n = (int*)((char*)d_ws + WS_FLN_OFF);
    int*                fflist   = (int*)((char*)d_ws + WS_FL_OFF);

    const int use_fl    = (ws_size >= WS_NEED_FL) ? 1 : 0;
    const int use_ffpre = (ws_size >= WS_NEED_FFD) ? 1 : 0;

    snn_init<<<64, 64, 0, stream>>>(ci, tmask, mb2);
    snn_ffmask<<<1000, 256, 0, stream>>>(inspk, ffmask);
    if (use_fl) {
        snn_fflist<<<250, 256, 0, stream>>>(ffmask, fflist, fflist_n);
        // ffdrive is filled by snn_run's fused staged pre-phase
    } else if (use_ffpre) {
        snn_ffpre<<<160 * 64, 64, 0, stream>>>(ffmask, Wff, sfff, ci, ffdrive);
    }
    snn_run<<<NBLK, 512, 0, stream>>>(W, Wff, sf, sfff, ci, out,
                                      ffmask, tmask, ffdrive,
                                      fflist, fflist_n,
                                      use_ffpre, use_fl, mb2);
}

// Round 17
// 1019.002 us; speedup vs baseline: 1.2783x; 1.2783x over previous
//
#include <hip/hip_runtime.h>
#include <cstdint>
#include <cstddef>

// Problem constants
#define N_NEU   4096
#define N_IN    1024
#define B_SZ    8
#define T_STEPS 500
#define NSLICE  16
#define NBLK    (B_SZ * NSLICE)     // 128 blocks, 256 threads, 1 post/thread
#define FF_WORDS (B_SZ * T_STEPS * 16)
#define FFP_STRIDE 33               // LDS row stride (odd: conflict-free)
#define FFP_CAP 128                 // per-tb list cap (mean actives ~51)
#define N_PAIRS (B_SZ * T_STEPS)    // 4000 (t,b) pairs

// ws layout:
//   [0)        u64 tmask[64]            512 B
//   [512)      u64 mb2[2][8][64][2]     16 KB  (tagged dbuf spike words)
//   [17408)    u64 ffmask[B*T*16]       512 KB (input-spike bitmasks)
//   [529408)   float ffdrive[T][B][N]   65.5 MB (precomputed FF drive)
//   [66065408) int fflist_n[4000]       16 KB  (true counts)
//   [66081792) int fflist[4000][128]    2 MB   (shared FULLY-padded lists)
#define WS_TM_OFF    0
#define WS_MB_OFF    512
#define WS_FFM_OFF   17408
#define WS_FFD_OFF   529408
#define WS_FLN_OFF   66065408
#define WS_FL_OFF    66081792
#define WS_NEED_FFD  (529408 + (size_t)T_STEPS * B_SZ * N_NEU * 4)   // old path
#define WS_NEED_FL   (66081792 + (size_t)N_PAIRS * FFP_CAP * 4)      // new path

__global__ __launch_bounds__(64) void snn_init(const int* __restrict__ ci,
                                               unsigned long long* __restrict__ tmask,
                                               unsigned long long* __restrict__ mb2) {
    const int k = blockIdx.x, l = threadIdx.x;   // 64 blocks x 64 threads
    unsigned long long m = __ballot(ci[(k << 6) + l] == 0);
    if (l == 0) tmask[k] = m;
    const int idx = (k << 6) + l;
    if (idx < 2048) mb2[idx] = 0ULL;             // tag 0 never matches t>=1
}

// input spikes (B,T,NI) -> bitmask words, 64 elems per word, ascending order
__global__ __launch_bounds__(256) void snn_ffmask(const float* __restrict__ inspk,
                                                  unsigned long long* __restrict__ ffmask) {
    int gid = blockIdx.x * 256 + threadIdx.x;
    int wid = gid >> 6, lane = gid & 63;
    int nw  = (gridDim.x * 256) >> 6;
    for (int w = wid; w < FF_WORDS; w += nw) {
        float v = inspk[(size_t)w * 64 + lane];
        unsigned long long m = __ballot(v > 0.5f);
        if (lane == 0) ffmask[w] = m;
    }
}

// Extract set-bit indices of a distributed 64x64-bit mask into lds as typed
// entries (idx<<2)|ty, globally ascending. Pads to a multiple of 64 with
// sentinels (ty 2). Returns real count.
__device__ __forceinline__ int extract_pad(unsigned long long m,
                                           unsigned long long tm_exc,
                                           int* lds, int lane) {
    int pc  = __popcll(m);
    int sum = pc;
#pragma unroll
    for (int d = 1; d < 64; d <<= 1) {
        int o = __shfl_up(sum, d, 64);
        if (lane >= d) sum += o;
    }
    int off   = sum - pc;           // exclusive prefix
    int total = __shfl(sum, 63, 64);
    int base  = lane << 6;
    while (m) {
        int bit = __builtin_ctzll(m);
        int ty  = ((tm_exc >> bit) & 1ULL) ? 0 : 1;
        lds[off++] = ((base + bit) << 2) | ty;
        m &= m - 1ULL;
    }
    int padcnt = (-total) & 63;
    if (lane < padcnt) lds[total + lane] = 2;   // sentinel: idx 0, ty 2
    return total;
}

// Capped extract (all ty0), FULL sentinel pad: every slot [total,128) gets a
// ty2 sentinel (R17: enables static 128-entry folds — no dynamic chunk count,
// no uninitialized reads). Returns TRUE count; caller uses slow path if >cap.
__device__ __forceinline__ int extract_cap(unsigned long long m,
                                           int* buf, int lane) {
    int pc  = __popcll(m);
    int sum = pc;
#pragma unroll
    for (int d = 1; d < 64; d <<= 1) {
        int o = __shfl_up(sum, d, 64);
        if (lane >= d) sum += o;
    }
    int off   = sum - pc;
    int total = __shfl(sum, 63, 64);
    int base  = lane << 6;
    while (m) {
        int bit = __builtin_ctzll(m);
        if (off < FFP_CAP) buf[off] = (base + bit) << 2;   // ty0
        ++off;
        m &= m - 1ULL;
    }
    for (int s = total + lane; s < FFP_CAP; s += 64)
        buf[s] = 2;                                        // sentinel ty2
    return total;
}

// Build the 4000 shared FF lists ONCE (R11 lesson: per-block re-extraction
// was the dominant ffpre cost).
__global__ __launch_bounds__(256) void snn_fflist(
    const unsigned long long* __restrict__ ffmask,
    int* __restrict__ fflist,
    int* __restrict__ fflist_n)
{
    const int lane = threadIdx.x & 63;
    const int wv   = threadIdx.x >> 6;
    const int w    = blockIdx.x * 4 + wv;      // 250 blocks x 4 waves = 1000
    for (int q = 0; q < 4; ++q) {
        const int p = w * 4 + q;               // pair index = t*8 + b
        const int t = p >> 3, b = p & 7;
        const unsigned long long mf =
            (lane < 16) ? ffmask[((size_t)b * T_STEPS + t) * 16 + lane] : 0ULL;
        const int n = extract_cap(mf, fflist + (size_t)p * FFP_CAP, lane);
        if (lane == 0) fflist_n[p] = n;
    }
}

// Combined typed gather (recurrent): proven pipelined structure. Unchanged.
__device__ __forceinline__ void gather2(const int* __restrict__ lst, int npad,
                                        const float* __restrict__ base,
                                        float se, float si,
                                        float* oe, float* oi) {
#pragma clang fp contract(off)
    float ae = 0.0f, ai = 0.0f;
    const int4* lst4 = (const int4*)lst;
    for (int k = 0; k < npad; k += 64) {
        int4  eq[16];
        int   e[64];
        float w[64];
#pragma unroll
        for (int u = 0; u < 16; ++u) eq[u] = lst4[(k >> 2) + u];
#pragma unroll
        for (int u = 0; u < 16; ++u) {
            e[4 * u + 0] = eq[u].x; e[4 * u + 1] = eq[u].y;
            e[4 * u + 2] = eq[u].z; e[4 * u + 3] = eq[u].w;
        }
#pragma unroll
        for (int u = 0; u < 64; ++u) w[u] = base[(size_t)(e[u] >> 2) << 12];
#pragma unroll
        for (int u = 0; u < 64; ++u) {
            const int ty = e[u] & 3;
            const float sc = (ty == 0) ? se : ((ty == 1) ? si : 0.0f);
            const float p  = w[u] * sc;           // per-element product rounding = W_eff
            ae = (ty == 0) ? ae + p : ae;
            ai = (ty == 1) ? ai + p : ai;
        }
    }
    *oe = ae; *oi = ai;
}

// FF precompute v6 (R17): staged-LDS tile + shared lists + STATIC 4x32-entry
// unrolled fold. R12-R15 lesson: the dynamic-count chunk loop serialized the
// per-pair fold (nf load -> nch -> dependent chunks, ~700cy each); with full
// sentinel padding the fold is a fixed 128 entries — static bounds, loads
// pipeline across batches. Extra sentinel folds are w*0.0 = +/-0 adds:
// bitwise identity (Wff >= +0 -> acc never -0); real entries fold in the
// same ascending order => bit-exact.
__global__ __launch_bounds__(1024) void snn_ffpre5(
    const unsigned long long* __restrict__ ffmask,
    const float* __restrict__ Wff,
    const float* __restrict__ sfff,
    const int*   __restrict__ ci,
    const int*   __restrict__ fflist,
    const int*   __restrict__ fflist_n,
    float*       __restrict__ ffdrive)
{
#pragma clang fp contract(off)
    const int tid = threadIdx.x;
    const int s   = blockIdx.x & 127;        // column slice [s*32, s*32+32)
    const int tbh = blockIdx.x >> 7;         // tb half: 0 or 1
    __shared__ float lwff[N_IN * FFP_STRIDE];   // 132 KB, stride-33 padded

    // stage Wff column-slice: 1024 threads, 32 rows in parallel, coalesced
    {
        const int j  = tid & 31;
        const int r0 = tid >> 5;             // 0..31
        for (int r = r0; r < N_IN; r += 32)
            lwff[r * FFP_STRIDE + j] = Wff[(size_t)r * N_NEU + (s << 5) + j];
    }
    __syncthreads();

    const int lane   = tid & 63;
    const int wv     = tid >> 6;             // 0..15
    const int j      = lane & 31;
    const int h      = lane >> 5;
    const int jg     = (s << 5) + j;
    const float sff  = sfff[ci[jg]];
    const int stream = (wv << 1) | h;        // 0..31 fold streams

    // 2000 pairs per block, 32 streams: pl = k*32 + stream
    for (int k = 0;; ++k) {
        const int pl = k * 32 + stream;
        if (pl >= 2000) break;               // wave-uniform (h pair exits together)
        const int p  = tbh * 2000 + pl;      // pair index = t*8 + b
        const int nf = fflist_n[p];
        float acc = 0.0f;
        if (nf <= FFP_CAP) {
            const int4* l4 = (const int4*)(fflist + (size_t)p * FFP_CAP);
#pragma unroll
            for (int bb = 0; bb < 4; ++bb) { // 4 STATIC batches of 32 entries
                int4 eq[8];
#pragma unroll
                for (int u = 0; u < 8; ++u) eq[u] = l4[bb * 8 + u];
                int e[32];
#pragma unroll
                for (int u = 0; u < 8; ++u) {
                    e[4 * u + 0] = eq[u].x; e[4 * u + 1] = eq[u].y;
                    e[4 * u + 2] = eq[u].z; e[4 * u + 3] = eq[u].w;
                }
                float w[32];
#pragma unroll
                for (int u = 0; u < 32; ++u)
                    w[u] = lwff[(e[u] >> 2) * FFP_STRIDE + j];
#pragma unroll
                for (int u = 0; u < 32; ++u) {
                    const float sc = ((e[u] & 3) == 0) ? sff : 0.0f;
                    const float pr = w[u] * sc;
                    acc += pr;               // ascending-i left fold
                }
            }
        } else {
            // exact slow path (P~1e-18 for this input): ascending bit-walk
            const int t = p >> 3, b = p & 7;
            const unsigned long long* mp =
                ffmask + ((size_t)b * T_STEPS + t) * 16;
            for (int w16 = 0; w16 < 16; ++w16) {
                unsigned long long mw = mp[w16];
                const int base = w16 << 6;
                while (mw) {
                    const int bit = __builtin_ctzll(mw); mw &= mw - 1ULL;
                    const float pr = lwff[(base + bit) * FFP_STRIDE + j] * sff;
                    acc += pr;
                }
            }
        }
        ffdrive[(size_t)p * N_NEU + jg] = acc;   // p == t*8+b == layout index
    }
}

// Old FF precompute (R6-proven, ~425us LLC-bound): workspace fallback only.
__global__ __launch_bounds__(64) void snn_ffpre(const unsigned long long* __restrict__ ffmask,
                                                const float* __restrict__ Wff,
                                                const float* __restrict__ sfff,
                                                const int*   __restrict__ ci,
                                                float*       __restrict__ ffdrive) {
#pragma clang fp contract(off)
    const int lane  = threadIdx.x;
    const int chunk = blockIdx.x & 63;
    const int tile  = blockIdx.x >> 6;     // 160 tiles of 25 (t,b) pairs
    const int i     = (chunk << 6) + lane;
    const float s_ff = sfff[ci[i]];
    __shared__ alignas(16) int lds_f[N_IN + 64];
    for (int p = tile * 25; p < tile * 25 + 25; ++p) {
        const int t = p >> 3, b = p & 7;
        const unsigned long long mf =
            (lane < 16) ? ffmask[((size_t)b * T_STEPS + t) * 16 + lane] : 0ULL;
        const int n = extract_pad(mf, ~0ULL, lds_f, lane);   // all ty0
        float fd, dummy;
        gather2(lds_f, (n + 63) & ~63, Wff + i, s_ff, 0.0f, &fd, &dummy);
        ffdrive[((size_t)t * B_SZ + b) * N_NEU + i] = fd;
    }
}

__global__ __launch_bounds__(256) void snn_run(
    const float* __restrict__ W,       // (N,N) row j = presyn
    const float* __restrict__ Wff,     // (NI,N)
    const float* __restrict__ sf,      // (2,2)
    const float* __restrict__ sfff,    // (1,2)
    const int*   __restrict__ ci,      // (N)
    float*       __restrict__ out,     // (B,T,N)
    const unsigned long long* __restrict__ ffmask,
    const unsigned long long* __restrict__ tmask_g,
    const float* __restrict__ ffdrive,
    int use_ffpre,
    unsigned long long* __restrict__ mb2)
{
#pragma clang fp contract(off)
    const int tid   = threadIdx.x;
    const int lane  = tid & 63;
    const int wv    = tid >> 6;
    const int bid   = blockIdx.x;
    // slice from bits {0,1,2,6}, batch from bits {3,4,5}
    const int slice = (((bid >> 6) & 1) << 3) | (bid & 7);
    const int b     = (bid >> 3) & 7;
    const int i     = (slice << 8) + (wv << 6) + lane;    // my post neuron
    const int c     = ci[i];

    const float s_exc = sf[c];
    const float s_inh = sf[2 + c];
    const float s_ff  = sfff[c];

    const unsigned long long my_tm = tmask_g[lane];

    // Per-wave private LDS regions: NO cross-wave sharing -> no barriers.
    __shared__ alignas(16) int lds_c[4][N_NEU + 64];
    __shared__ alignas(16) int lds_f[4][N_IN + 64];
    int* const my_ldsc = lds_c[wv];
    int* const my_ldsf = lds_f[wv];

    // mb2 layout (u64 units): [parity][batch][entry=(slice<<2)|wv][half]
    unsigned long long* const mbB = mb2 + (size_t)b * 128;

    float v = -70.0f, rf = 0.0f;
    float h0 = 0.0f, h1 = 0.0f, h2 = 0.0f, h3 = 0.0f;
    float g0 = 0.0f, g1 = 0.0f, g2 = 0.0f, g3 = 0.0f;

    const float aR0 = expf(-0.1f / 0.5f);
    const float aR1 = expf(-0.1f / 2.0f);
    const float aD0 = expf(-0.1f / 2.0f);
    const float aD1 = expf(-0.1f / 100.0f);
    const float aD2 = expf(-0.1f / 5.0f);
    const float kmem   = c ? (0.1f / 10.0f) : (0.1f / 20.0f);
    const float rsteps = c ? 10.0f : 20.0f;

    // warming base: this wave's 256B segment start within any W row
    const float* const wseg = W + (size_t)((slice << 8) + (wv << 6));

    for (int t = 0; t < T_STEPS; ++t) {
        // ffdrive issued BEFORE the poll: its ~600cy latency hides under
        // detection. asm keep-alive pins the load above the poll loop.
        float ffd = 0.0f;
        if (use_ffpre) {
            ffd = ffdrive[((size_t)t * B_SZ + b) * N_NEU + i];
            asm volatile("" :: "v"(ffd));
        }

        unsigned long long mw = 0ULL;
        if (t > 0) {
            // tagged single-hop poll: lane l owns entry l; parity dbuf; no
            // ABA (publish(t+2) requires every block past poll(t)).
            const unsigned int tg = (unsigned int)t;
            const unsigned long long* ep =
                mbB + (size_t)(t & 1) * 1024 + ((size_t)lane << 1);
            unsigned long long w0, w1;
            for (;;) {
                w0 = __hip_atomic_load(&ep[0], __ATOMIC_RELAXED,
                                       __HIP_MEMORY_SCOPE_AGENT);
                w1 = __hip_atomic_load(&ep[1], __ATOMIC_RELAXED,
                                       __HIP_MEMORY_SCOPE_AGENT);
                const bool ok = ((unsigned int)(w0 >> 32) == tg) &&
                                ((unsigned int)(w1 >> 32) == tg);
                if (__ballot(ok) == ~0ULL) break;
                __builtin_amdgcn_s_sleep(1);
            }
            mw = (w0 & 0xFFFFFFFFULL) | ((w1 & 0xFFFFFFFFULL) << 32);
            asm volatile("" ::: "memory");   // keep LDS writes below poll
        }

        // ---- line warming: pull this step's W row-segments toward L1 while
        // the extract scan runs; real gather loads MSHR-merge.
        {
            unsigned long long mm = mw;
            float wacc = 0.0f;
            const size_t rowbase = (size_t)lane << 18;  // (lane*64)<<12 floats
            while (mm) {
                const int bit = __builtin_ctzll(mm); mm &= mm - 1ULL;
                const float* r = wseg + rowbase + ((size_t)bit << 12);
                wacc += r[0]; wacc += r[16]; wacc += r[32]; wacc += r[48];
            }
            asm volatile("" :: "v"(wacc));
        }

        // zero-skip: fully-silent network step -> no extract scan needed.
        int ne = 0;
        if (__ballot(mw != 0ULL) != 0ULL)
            ne = extract_pad(mw, my_tm, my_ldsc, lane);

        if (!use_ffpre) {
            const unsigned long long mf =
                (lane < 16) ? ffmask[((size_t)b * T_STEPS + t) * 16 + lane] : 0ULL;
            const int nf = extract_pad(mf, ~0ULL, my_ldsf, lane);
            float fd, dummy;
            gather2(my_ldsf, (nf + 63) & ~63, Wff + i, s_ff, 0.0f, &fd, &dummy);
            ffd = fd;
        }

        float exc, inh;
        gather2(my_ldsc, (ne + 63) & ~63, W + i, s_exc, s_inh, &exc, &inh);

        // ---- neuron update (identical fp op sequence to R0-R16: bit-exact) ----
        const float d0 = exc;
        const float d1 = 0.5f * exc;
        const float d2 = inh;
        const float d3 = ffd;

        h0 = fmaf(h0, aR0, d0);
        h1 = fmaf(h1, aR1, d1);
        h2 = fmaf(h2, aR0, d2);
        h3 = fmaf(h3, aR0, d3);
        g0 = fmaf(g0, aD0, (1.0f - aD0) * h0);
        g1 = fmaf(g1, aD1, (1.0f - aD1) * h1);
        g2 = fmaf(g2, aD2, (1.0f - aD2) * h2);
        g3 = fmaf(g3, aD0, (1.0f - aD0) * h3);

        const float p0 = g0 * (0.0f - v);
        const float p1 = g1 * (0.0f - v);
        const float p2 = g2 * (-80.0f - v);
        const float p3 = g3 * (0.0f - v);
        const float Isyn = ((p0 + p1) + p2) + p3;

        float vn = fmaf(kmem, (-70.0f - v) + Isyn / 10.0f, v);
        const bool refr = rf > 0.0f;
        if (refr) vn = -65.0f;
        const float sn = (!refr && (vn > -50.0f)) ? 1.0f : 0.0f;
        const bool spk = sn > 0.5f;

        // publish at the EARLIEST instant: right after the spike decision,
        // before v/rf bookkeeping and the out store. Fire-and-forget.
        const unsigned long long sm = __ballot(spk);
        if (lane == 0) {
            const unsigned long long tg =
                (unsigned long long)(unsigned int)(t + 1) << 32;
            unsigned long long* pp = mb2 + (size_t)((t + 1) & 1) * 1024
                                   + (size_t)b * 128
                                   + ((size_t)((slice << 2) | wv) << 1);
            __hip_atomic_store(&pp[0], tg | (sm & 0xFFFFFFFFULL),
                               __ATOMIC_RELAXED, __HIP_MEMORY_SCOPE_AGENT);
            __hip_atomic_store(&pp[1], tg | (sm >> 32),
                               __ATOMIC_RELAXED, __HIP_MEMORY_SCOPE_AGENT);
        }

        v  = spk ? -65.0f : vn;
        rf = spk ? rsteps : fmaxf(rf - 1.0f, 0.0f);
        out[((size_t)b * T_STEPS + t) * N_NEU + i] = sn;   // regular store
    }
}

extern "C" void kernel_launch(void* const* d_in, const int* in_sizes, int n_in,
                              void* d_out, int out_size, void* d_ws, size_t ws_size,
                              hipStream_t stream) {
    const float* inspk = (const float*)d_in[0];
    const float* W     = (const float*)d_in[1];
    const float* Wff   = (const float*)d_in[2];
    const float* sf    = (const float*)d_in[3];
    const float* sfff  = (const float*)d_in[4];
    const int*   ci    = (const int*)d_in[5];

    float* out = (float*)d_out;
    unsigned long long* tmask    = (unsigned long long*)((char*)d_ws + WS_TM_OFF);
    unsigned long long* mb2      = (unsigned long long*)((char*)d_ws + WS_MB_OFF);
    unsigned long long* ffmask   = (unsigned long long*)((char*)d_ws + WS_FFM_OFF);
    float*              ffdrive  = (float*)((char*)d_ws + WS_FFD_OFF);
    int*                fflist_n = (int*)((char*)d_ws + WS_FLN_OFF);
    int*                fflist   = (int*)((char*)d_ws + WS_FL_OFF);

    const int use_fl    = (ws_size >= WS_NEED_FL) ? 1 : 0;
    const int use_ffpre = (ws_size >= WS_NEED_FFD) ? 1 : 0;

    snn_init<<<64, 64, 0, stream>>>(ci, tmask, mb2);
    snn_ffmask<<<1000, 256, 0, stream>>>(inspk, ffmask);
    if (use_fl) {
        snn_fflist<<<250, 256, 0, stream>>>(ffmask, fflist, fflist_n);
        snn_ffpre5<<<256, 1024, 0, stream>>>(ffmask, Wff, sfff, ci,
                                             fflist, fflist_n, ffdrive);
    } else if (use_ffpre) {
        snn_ffpre<<<160 * 64, 64, 0, stream>>>(ffmask, Wff, sfff, ci, ffdrive);
    }
    snn_run<<<NBLK, 256, 0, stream>>>(W, Wff, sf, sfff, ci, out,
                                      ffmask, tmask, ffdrive, use_ffpre, mb2);
}

// Round 18
// 877.761 us; speedup vs baseline: 1.4840x; 1.1609x over previous
//
#include <hip/hip_runtime.h>
#include <cstdint>
#include <cstddef>

// Problem constants
#define N_NEU   4096
#define N_IN    1024
#define B_SZ    8
#define T_STEPS 500
#define NSLICE  16
#define NBLK    (B_SZ * NSLICE)     // 128 blocks, 256 threads, 1 post/thread
#define FF_WORDS (B_SZ * T_STEPS * 16)
#define FFP_STRIDE 33               // LDS row stride (odd: conflict-free)
#define FFP_CAP 128                 // per-tb list cap (mean actives ~51)
#define N_PAIRS (B_SZ * T_STEPS)    // 4000 (t,b) pairs

// ws layout:
//   [0)        u64 tmask[64]            512 B
//   [512)      u64 mb2[2][8][64][2]     16 KB  (tagged dbuf spike words)
//   [17408)    u64 ffmask[B*T*16]       512 KB (input-spike bitmasks)
//   [529408)   float ffdrive[T][B][N]   65.5 MB (precomputed FF drive)
//   [66065408) int fflist_n[4000]       16 KB  (true counts)
//   [66081792) int fflist[4000][128]    2 MB   (shared padded lists)
#define WS_TM_OFF    0
#define WS_MB_OFF    512
#define WS_FFM_OFF   17408
#define WS_FFD_OFF   529408
#define WS_FLN_OFF   66065408
#define WS_FL_OFF    66081792
#define WS_NEED_FFD  (529408 + (size_t)T_STEPS * B_SZ * N_NEU * 4)   // old path
#define WS_NEED_FL   (66081792 + (size_t)N_PAIRS * FFP_CAP * 4)      // new path

__global__ __launch_bounds__(64) void snn_init(const int* __restrict__ ci,
                                               unsigned long long* __restrict__ tmask,
                                               unsigned long long* __restrict__ mb2) {
    const int k = blockIdx.x, l = threadIdx.x;   // 64 blocks x 64 threads
    unsigned long long m = __ballot(ci[(k << 6) + l] == 0);
    if (l == 0) tmask[k] = m;
    const int idx = (k << 6) + l;
    if (idx < 2048) mb2[idx] = 0ULL;             // tag 0 never matches t>=1
}

// input spikes (B,T,NI) -> bitmask words, 64 elems per word, ascending order
__global__ __launch_bounds__(256) void snn_ffmask(const float* __restrict__ inspk,
                                                  unsigned long long* __restrict__ ffmask) {
    int gid = blockIdx.x * 256 + threadIdx.x;
    int wid = gid >> 6, lane = gid & 63;
    int nw  = (gridDim.x * 256) >> 6;
    for (int w = wid; w < FF_WORDS; w += nw) {
        float v = inspk[(size_t)w * 64 + lane];
        unsigned long long m = __ballot(v > 0.5f);
        if (lane == 0) ffmask[w] = m;
    }
}

// Extract set-bit indices of a distributed 64x64-bit mask into lds as typed
// entries (idx<<2)|ty, globally ascending. Pads to a multiple of 64 with
// sentinels (ty 2). Returns real count.
__device__ __forceinline__ int extract_pad(unsigned long long m,
                                           unsigned long long tm_exc,
                                           int* lds, int lane) {
    int pc  = __popcll(m);
    int sum = pc;
#pragma unroll
    for (int d = 1; d < 64; d <<= 1) {
        int o = __shfl_up(sum, d, 64);
        if (lane >= d) sum += o;
    }
    int off   = sum - pc;           // exclusive prefix
    int total = __shfl(sum, 63, 64);
    int base  = lane << 6;
    while (m) {
        int bit = __builtin_ctzll(m);
        int ty  = ((tm_exc >> bit) & 1ULL) ? 0 : 1;
        lds[off++] = ((base + bit) << 2) | ty;
        m &= m - 1ULL;
    }
    int padcnt = (-total) & 63;
    if (lane < padcnt) lds[total + lane] = 2;   // sentinel: idx 0, ty 2
    return total;
}

// Capped extract (all ty0) with write guard — safe into a 128-slot buffer.
// Pads to the next 64-multiple (sentinels ty2). Returns TRUE count.
__device__ __forceinline__ int extract_cap(unsigned long long m,
                                           int* buf, int lane) {
    int pc  = __popcll(m);
    int sum = pc;
#pragma unroll
    for (int d = 1; d < 64; d <<= 1) {
        int o = __shfl_up(sum, d, 64);
        if (lane >= d) sum += o;
    }
    int off   = sum - pc;
    int total = __shfl(sum, 63, 64);
    int base  = lane << 6;
    while (m) {
        int bit = __builtin_ctzll(m);
        if (off < FFP_CAP) buf[off] = (base + bit) << 2;   // ty0
        ++off;
        m &= m - 1ULL;
    }
    if (total < FFP_CAP) {
        int padcnt = (-total) & 63;
        if (lane < padcnt && total + lane < FFP_CAP)
            buf[total + lane] = 2;                         // sentinel ty2
    }
    return total;
}

// Build the 4000 shared FF lists ONCE (R11 lesson: per-block re-extraction
// was the dominant ffpre cost).
__global__ __launch_bounds__(256) void snn_fflist(
    const unsigned long long* __restrict__ ffmask,
    int* __restrict__ fflist,
    int* __restrict__ fflist_n)
{
    const int lane = threadIdx.x & 63;
    const int wv   = threadIdx.x >> 6;
    const int w    = blockIdx.x * 4 + wv;      // 250 blocks x 4 waves = 1000
    for (int q = 0; q < 4; ++q) {
        const int p = w * 4 + q;               // pair index = t*8 + b
        const int t = p >> 3, b = p & 7;
        const unsigned long long mf =
            (lane < 16) ? ffmask[((size_t)b * T_STEPS + t) * 16 + lane] : 0ULL;
        const int n = extract_cap(mf, fflist + (size_t)p * FFP_CAP, lane);
        if (lane == 0) fflist_n[p] = n;
    }
}

// Combined typed gather (recurrent): proven pipelined structure. Unchanged.
__device__ __forceinline__ void gather2(const int* __restrict__ lst, int npad,
                                        const float* __restrict__ base,
                                        float se, float si,
                                        float* oe, float* oi) {
#pragma clang fp contract(off)
    float ae = 0.0f, ai = 0.0f;
    const int4* lst4 = (const int4*)lst;
    for (int k = 0; k < npad; k += 64) {
        int4  eq[16];
        int   e[64];
        float w[64];
#pragma unroll
        for (int u = 0; u < 16; ++u) eq[u] = lst4[(k >> 2) + u];
#pragma unroll
        for (int u = 0; u < 16; ++u) {
            e[4 * u + 0] = eq[u].x; e[4 * u + 1] = eq[u].y;
            e[4 * u + 2] = eq[u].z; e[4 * u + 3] = eq[u].w;
        }
#pragma unroll
        for (int u = 0; u < 64; ++u) w[u] = base[(size_t)(e[u] >> 2) << 12];
#pragma unroll
        for (int u = 0; u < 64; ++u) {
            const int ty = e[u] & 3;
            const float sc = (ty == 0) ? se : ((ty == 1) ? si : 0.0f);
            const float p  = w[u] * sc;           // per-element product rounding = W_eff
            ae = (ty == 0) ? ae + p : ae;
            ai = (ty == 1) ? ai + p : ai;
        }
    }
    *oe = ae; *oi = ai;
}

// FF precompute v5 (R15 form — converged): staged-LDS Wff tile + shared
// lists, 1024 threads (4 waves/SIMD), dynamic 16-entry chunk fold. Measured
// ~290us, within 2x of the gathered-LDS-read floor (~150us); static overfold
// (R17) and all structural alternatives measured worse.
__global__ __launch_bounds__(1024) void snn_ffpre5(
    const unsigned long long* __restrict__ ffmask,
    const float* __restrict__ Wff,
    const float* __restrict__ sfff,
    const int*   __restrict__ ci,
    const int*   __restrict__ fflist,
    const int*   __restrict__ fflist_n,
    float*       __restrict__ ffdrive)
{
#pragma clang fp contract(off)
    const int tid = threadIdx.x;
    const int s   = blockIdx.x & 127;        // column slice [s*32, s*32+32)
    const int tbh = blockIdx.x >> 7;         // tb half: 0 or 1
    __shared__ float lwff[N_IN * FFP_STRIDE];   // 132 KB, stride-33 padded

    // stage Wff column-slice: 1024 threads, 32 rows in parallel, coalesced
    {
        const int j  = tid & 31;
        const int r0 = tid >> 5;             // 0..31
        for (int r = r0; r < N_IN; r += 32)
            lwff[r * FFP_STRIDE + j] = Wff[(size_t)r * N_NEU + (s << 5) + j];
    }
    __syncthreads();

    const int lane   = tid & 63;
    const int wv     = tid >> 6;             // 0..15
    const int j      = lane & 31;
    const int h      = lane >> 5;
    const int jg     = (s << 5) + j;
    const float sff  = sfff[ci[jg]];
    const int stream = (wv << 1) | h;        // 0..31 fold streams

    // 2000 pairs per block, 32 streams: pl = k*32 + stream
    for (int k = 0;; ++k) {
        const int pl = k * 32 + stream;
        if (pl >= 2000) break;               // wave-uniform (h pair exits together)
        const int p  = tbh * 2000 + pl;      // pair index = t*8 + b
        const int nf = fflist_n[p];
        float acc = 0.0f;
        if (nf <= FFP_CAP) {
            const int4* l4 = (const int4*)(fflist + (size_t)p * FFP_CAP);
            const int nch = (nf + 15) >> 4;  // 16-entry chunks
            for (int c = 0; c < nch; ++c) {
                int4 eq[4];
#pragma unroll
                for (int u = 0; u < 4; ++u) eq[u] = l4[c * 4 + u];
                int e[16];
#pragma unroll
                for (int u = 0; u < 4; ++u) {
                    e[4 * u + 0] = eq[u].x; e[4 * u + 1] = eq[u].y;
                    e[4 * u + 2] = eq[u].z; e[4 * u + 3] = eq[u].w;
                }
                float w[16];
#pragma unroll
                for (int u = 0; u < 16; ++u)
                    w[u] = lwff[(e[u] >> 2) * FFP_STRIDE + j];
#pragma unroll
                for (int u = 0; u < 16; ++u) {
                    const float sc = ((e[u] & 3) == 0) ? sff : 0.0f;
                    const float pr = w[u] * sc;
                    acc += pr;               // ascending-i left fold
                }
            }
        } else {
            // exact slow path (P~1e-18 for this input): ascending bit-walk
            const int t = p >> 3, b = p & 7;
            const unsigned long long* mp =
                ffmask + ((size_t)b * T_STEPS + t) * 16;
            for (int w16 = 0; w16 < 16; ++w16) {
                unsigned long long mw = mp[w16];
                const int base = w16 << 6;
                while (mw) {
                    const int bit = __builtin_ctzll(mw); mw &= mw - 1ULL;
                    const float pr = lwff[(base + bit) * FFP_STRIDE + j] * sff;
                    acc += pr;
                }
            }
        }
        ffdrive[(size_t)p * N_NEU + jg] = acc;   // p == t*8+b == layout index
    }
}

// Old FF precompute (R6-proven, ~425us LLC-bound): workspace fallback only.
__global__ __launch_bounds__(64) void snn_ffpre(const unsigned long long* __restrict__ ffmask,
                                                const float* __restrict__ Wff,
                                                const float* __restrict__ sfff,
                                                const int*   __restrict__ ci,
                                                float*       __restrict__ ffdrive) {
#pragma clang fp contract(off)
    const int lane  = threadIdx.x;
    const int chunk = blockIdx.x & 63;
    const int tile  = blockIdx.x >> 6;     // 160 tiles of 25 (t,b) pairs
    const int i     = (chunk << 6) + lane;
    const float s_ff = sfff[ci[i]];
    __shared__ alignas(16) int lds_f[N_IN + 64];
    for (int p = tile * 25; p < tile * 25 + 25; ++p) {
        const int t = p >> 3, b = p & 7;
        const unsigned long long mf =
            (lane < 16) ? ffmask[((size_t)b * T_STEPS + t) * 16 + lane] : 0ULL;
        const int n = extract_pad(mf, ~0ULL, lds_f, lane);   // all ty0
        float fd, dummy;
        gather2(lds_f, (n + 63) & ~63, Wff + i, s_ff, 0.0f, &fd, &dummy);
        ffdrive[((size_t)t * B_SZ + b) * N_NEU + i] = fd;
    }
}

__global__ __launch_bounds__(256) void snn_run(
    const float* __restrict__ W,       // (N,N) row j = presyn
    const float* __restrict__ Wff,     // (NI,N)
    const float* __restrict__ sf,      // (2,2)
    const float* __restrict__ sfff,    // (1,2)
    const int*   __restrict__ ci,      // (N)
    float*       __restrict__ out,     // (B,T,N)
    const unsigned long long* __restrict__ ffmask,
    const unsigned long long* __restrict__ tmask_g,
    const float* __restrict__ ffdrive,
    int use_ffpre,
    unsigned long long* __restrict__ mb2)
{
#pragma clang fp contract(off)
    const int tid   = threadIdx.x;
    const int lane  = tid & 63;
    const int wv    = tid >> 6;
    const int bid   = blockIdx.x;
    // slice from bits {0,1,2,6}, batch from bits {3,4,5}
    const int slice = (((bid >> 6) & 1) << 3) | (bid & 7);
    const int b     = (bid >> 3) & 7;
    const int i     = (slice << 8) + (wv << 6) + lane;    // my post neuron
    const int c     = ci[i];

    const float s_exc = sf[c];
    const float s_inh = sf[2 + c];
    const float s_ff  = sfff[c];

    const unsigned long long my_tm = tmask_g[lane];

    // Per-wave private LDS regions: NO cross-wave sharing -> no barriers.
    __shared__ alignas(16) int lds_c[4][N_NEU + 64];
    __shared__ alignas(16) int lds_f[4][N_IN + 64];
    int* const my_ldsc = lds_c[wv];
    int* const my_ldsf = lds_f[wv];

    // mb2 layout (u64 units): [parity][batch][entry=(slice<<2)|wv][half]
    unsigned long long* const mbB = mb2 + (size_t)b * 128;

    float v = -70.0f, rf = 0.0f;
    float h0 = 0.0f, h1 = 0.0f, h2 = 0.0f, h3 = 0.0f;
    float g0 = 0.0f, g1 = 0.0f, g2 = 0.0f, g3 = 0.0f;

    const float aR0 = expf(-0.1f / 0.5f);
    const float aR1 = expf(-0.1f / 2.0f);
    const float aD0 = expf(-0.1f / 2.0f);
    const float aD1 = expf(-0.1f / 100.0f);
    const float aD2 = expf(-0.1f / 5.0f);
    const float kmem   = c ? (0.1f / 10.0f) : (0.1f / 20.0f);
    const float rsteps = c ? 10.0f : 20.0f;

    // warming base: this wave's 256B segment start within any W row
    const float* const wseg = W + (size_t)((slice << 8) + (wv << 6));

    for (int t = 0; t < T_STEPS; ++t) {
        // ffdrive issued BEFORE the poll: its ~600cy latency hides under
        // detection. asm keep-alive pins the load above the poll loop.
        float ffd = 0.0f;
        if (use_ffpre) {
            ffd = ffdrive[((size_t)t * B_SZ + b) * N_NEU + i];
            asm volatile("" :: "v"(ffd));
        }

        unsigned long long mw = 0ULL;
        if (t > 0) {
            // tagged single-hop poll: lane l owns entry l; parity dbuf; no
            // ABA (publish(t+2) requires every block past poll(t)).
            // R18: HOT spin (no s_sleep) — retry rate is self-limited by the
            // ~500cy LLC load RT, so traffic stays trivial while the ~64cy
            // sleep quantization + overshoot disappears from the step cycle.
            const unsigned int tg = (unsigned int)t;
            const unsigned long long* ep =
                mbB + (size_t)(t & 1) * 1024 + ((size_t)lane << 1);
            unsigned long long w0, w1;
            for (;;) {
                w0 = __hip_atomic_load(&ep[0], __ATOMIC_RELAXED,
                                       __HIP_MEMORY_SCOPE_AGENT);
                w1 = __hip_atomic_load(&ep[1], __ATOMIC_RELAXED,
                                       __HIP_MEMORY_SCOPE_AGENT);
                const bool ok = ((unsigned int)(w0 >> 32) == tg) &&
                                ((unsigned int)(w1 >> 32) == tg);
                if (__ballot(ok) == ~0ULL) break;
            }
            mw = (w0 & 0xFFFFFFFFULL) | ((w1 & 0xFFFFFFFFULL) << 32);
            asm volatile("" ::: "memory");   // keep LDS writes below poll
        }

        // ---- line warming: pull this step's W row-segments toward L1 while
        // the extract scan runs; real gather loads MSHR-merge.
        {
            unsigned long long mm = mw;
            float wacc = 0.0f;
            const size_t rowbase = (size_t)lane << 18;  // (lane*64)<<12 floats
            while (mm) {
                const int bit = __builtin_ctzll(mm); mm &= mm - 1ULL;
                const float* r = wseg + rowbase + ((size_t)bit << 12);
                wacc += r[0]; wacc += r[16]; wacc += r[32]; wacc += r[48];
            }
            asm volatile("" :: "v"(wacc));
        }

        // zero-skip: fully-silent network step -> no extract scan needed.
        int ne = 0;
        if (__ballot(mw != 0ULL) != 0ULL)
            ne = extract_pad(mw, my_tm, my_ldsc, lane);

        if (!use_ffpre) {
            const unsigned long long mf =
                (lane < 16) ? ffmask[((size_t)b * T_STEPS + t) * 16 + lane] : 0ULL;
            const int nf = extract_pad(mf, ~0ULL, my_ldsf, lane);
            float fd, dummy;
            gather2(my_ldsf, (nf + 63) & ~63, Wff + i, s_ff, 0.0f, &fd, &dummy);
            ffd = fd;
        }

        float exc, inh;
        gather2(my_ldsc, (ne + 63) & ~63, W + i, s_exc, s_inh, &exc, &inh);

        // ---- neuron update (identical fp op sequence to R0-R17: bit-exact) ----
        const float d0 = exc;
        const float d1 = 0.5f * exc;
        const float d2 = inh;
        const float d3 = ffd;

        h0 = fmaf(h0, aR0, d0);
        h1 = fmaf(h1, aR1, d1);
        h2 = fmaf(h2, aR0, d2);
        h3 = fmaf(h3, aR0, d3);
        g0 = fmaf(g0, aD0, (1.0f - aD0) * h0);
        g1 = fmaf(g1, aD1, (1.0f - aD1) * h1);
        g2 = fmaf(g2, aD2, (1.0f - aD2) * h2);
        g3 = fmaf(g3, aD0, (1.0f - aD0) * h3);

        const float p0 = g0 * (0.0f - v);
        const float p1 = g1 * (0.0f - v);
        const float p2 = g2 * (-80.0f - v);
        const float p3 = g3 * (0.0f - v);
        const float Isyn = ((p0 + p1) + p2) + p3;

        float vn = fmaf(kmem, (-70.0f - v) + Isyn / 10.0f, v);
        const bool refr = rf > 0.0f;
        if (refr) vn = -65.0f;
        const float sn = (!refr && (vn > -50.0f)) ? 1.0f : 0.0f;
        const bool spk = sn > 0.5f;

        // publish at the EARLIEST instant: right after the spike decision,
        // before v/rf bookkeeping and the out store. Fire-and-forget.
        const unsigned long long sm = __ballot(spk);
        if (lane == 0) {
            const unsigned long long tg =
                (unsigned long long)(unsigned int)(t + 1) << 32;
            unsigned long long* pp = mb2 + (size_t)((t + 1) & 1) * 1024
                                   + (size_t)b * 128
                                   + ((size_t)((slice << 2) | wv) << 1);
            __hip_atomic_store(&pp[0], tg | (sm & 0xFFFFFFFFULL),
                               __ATOMIC_RELAXED, __HIP_MEMORY_SCOPE_AGENT);
            __hip_atomic_store(&pp[1], tg | (sm >> 32),
                               __ATOMIC_RELAXED, __HIP_MEMORY_SCOPE_AGENT);
        }

        v  = spk ? -65.0f : vn;
        rf = spk ? rsteps : fmaxf(rf - 1.0f, 0.0f);
        out[((size_t)b * T_STEPS + t) * N_NEU + i] = sn;   // regular store
    }
}

extern "C" void kernel_launch(void* const* d_in, const int* in_sizes, int n_in,
                              void* d_out, int out_size, void* d_ws, size_t ws_size,
                              hipStream_t stream) {
    const float* inspk = (const float*)d_in[0];
    const float* W     = (const float*)d_in[1];
    const float* Wff   = (const float*)d_in[2];
    const float* sf    = (const float*)d_in[3];
    const float* sfff  = (const float*)d_in[4];
    const int*   ci    = (const int*)d_in[5];

    float* out = (float*)d_out;
    unsigned long long* tmask    = (unsigned long long*)((char*)d_ws + WS_TM_OFF);
    unsigned long long* mb2      = (unsigned long long*)((char*)d_ws + WS_MB_OFF);
    unsigned long long* ffmask   = (unsigned long long*)((char*)d_ws + WS_FFM_OFF);
    float*              ffdrive  = (float*)((char*)d_ws + WS_FFD_OFF);
    int*                fflist_n = (int*)((char*)d_ws + WS_FLN_OFF);
    int*                fflist   = (int*)((char*)d_ws + WS_FL_OFF);

    const int use_fl    = (ws_size >= WS_NEED_FL) ? 1 : 0;
    const int use_ffpre = (ws_size >= WS_NEED_FFD) ? 1 : 0;

    snn_init<<<64, 64, 0, stream>>>(ci, tmask, mb2);
    snn_ffmask<<<1000, 256, 0, stream>>>(inspk, ffmask);
    if (use_fl) {
        snn_fflist<<<250, 256, 0, stream>>>(ffmask, fflist, fflist_n);
        snn_ffpre5<<<256, 1024, 0, stream>>>(ffmask, Wff, sfff, ci,
                                             fflist, fflist_n, ffdrive);
    } else if (use_ffpre) {
        snn_ffpre<<<160 * 64, 64, 0, stream>>>(ffmask, Wff, sfff, ci, ffdrive);
    }
    snn_run<<<NBLK, 256, 0, stream>>>(W, Wff, sf, sfff, ci, out,
                                      ffmask, tmask, ffdrive, use_ffpre, mb2);
}

// Round 19
// 872.562 us; speedup vs baseline: 1.4929x; 1.0060x over previous
//
#include <hip/hip_runtime.h>
#include <cstdint>
#include <cstddef>

// Problem constants
#define N_NEU   4096
#define N_IN    1024
#define B_SZ    8
#define T_STEPS 500
#define NSLICE  16
#define NBLK    (B_SZ * NSLICE)     // 128 blocks, 256 threads, 1 post/thread
#define FF_WORDS (B_SZ * T_STEPS * 16)
#define FFP_STRIDE 33               // LDS row stride (odd: conflict-free)
#define FFP_CAP 128                 // per-tb list cap (mean actives ~51)
#define N_PAIRS (B_SZ * T_STEPS)    // 4000 (t,b) pairs

// ws layout:
//   [0)        u64 tmask[64]            512 B
//   [512)      u64 mb2[2][8][64][2]     16 KB  (tagged dbuf spike words)
//   [17408)    u64 ffmask[B*T*16]       512 KB (input-spike bitmasks)
//   [529408)   float ffdrive[T][B][N]   65.5 MB (precomputed FF drive)
//   [66065408) int fflist_n[4000]       16 KB  (true counts)
//   [66081792) int fflist[4000][128]    2 MB   (shared padded lists)
#define WS_TM_OFF    0
#define WS_MB_OFF    512
#define WS_FFM_OFF   17408
#define WS_FFD_OFF   529408
#define WS_FLN_OFF   66065408
#define WS_FL_OFF    66081792
#define WS_NEED_FFD  (529408 + (size_t)T_STEPS * B_SZ * N_NEU * 4)   // old path
#define WS_NEED_FL   (66081792 + (size_t)N_PAIRS * FFP_CAP * 4)      // new path

__global__ __launch_bounds__(64) void snn_init(const int* __restrict__ ci,
                                               unsigned long long* __restrict__ tmask,
                                               unsigned long long* __restrict__ mb2) {
    const int k = blockIdx.x, l = threadIdx.x;   // 64 blocks x 64 threads
    unsigned long long m = __ballot(ci[(k << 6) + l] == 0);
    if (l == 0) tmask[k] = m;
    const int idx = (k << 6) + l;
    if (idx < 2048) mb2[idx] = 0ULL;             // tag 0 never matches t>=1
}

// input spikes (B,T,NI) -> bitmask words, 64 elems per word, ascending order
// (fallback path only; the use_fl path uses snn_ffboth below)
__global__ __launch_bounds__(256) void snn_ffmask(const float* __restrict__ inspk,
                                                  unsigned long long* __restrict__ ffmask) {
    int gid = blockIdx.x * 256 + threadIdx.x;
    int wid = gid >> 6, lane = gid & 63;
    int nw  = (gridDim.x * 256) >> 6;
    for (int w = wid; w < FF_WORDS; w += nw) {
        float v = inspk[(size_t)w * 64 + lane];
        unsigned long long m = __ballot(v > 0.5f);
        if (lane == 0) ffmask[w] = m;
    }
}

// Extract set-bit indices of a distributed 64x64-bit mask into lds as typed
// entries (idx<<2)|ty, globally ascending. Pads to a multiple of 64 with
// sentinels (ty 2). Returns real count.
__device__ __forceinline__ int extract_pad(unsigned long long m,
                                           unsigned long long tm_exc,
                                           int* lds, int lane) {
    int pc  = __popcll(m);
    int sum = pc;
#pragma unroll
    for (int d = 1; d < 64; d <<= 1) {
        int o = __shfl_up(sum, d, 64);
        if (lane >= d) sum += o;
    }
    int off   = sum - pc;           // exclusive prefix
    int total = __shfl(sum, 63, 64);
    int base  = lane << 6;
    while (m) {
        int bit = __builtin_ctzll(m);
        int ty  = ((tm_exc >> bit) & 1ULL) ? 0 : 1;
        lds[off++] = ((base + bit) << 2) | ty;
        m &= m - 1ULL;
    }
    int padcnt = (-total) & 63;
    if (lane < padcnt) lds[total + lane] = 2;   // sentinel: idx 0, ty 2
    return total;
}

// Capped extract (all ty0) with write guard — safe into a 128-slot buffer.
// Pads to the next 64-multiple (sentinels ty2). Returns TRUE count.
__device__ __forceinline__ int extract_cap(unsigned long long m,
                                           int* buf, int lane) {
    int pc  = __popcll(m);
    int sum = pc;
#pragma unroll
    for (int d = 1; d < 64; d <<= 1) {
        int o = __shfl_up(sum, d, 64);
        if (lane >= d) sum += o;
    }
    int off   = sum - pc;
    int total = __shfl(sum, 63, 64);
    int base  = lane << 6;
    while (m) {
        int bit = __builtin_ctzll(m);
        if (off < FFP_CAP) buf[off] = (base + bit) << 2;   // ty0
        ++off;
        m &= m - 1ULL;
    }
    if (total < FFP_CAP) {
        int padcnt = (-total) & 63;
        if (lane < padcnt && total + lane < FFP_CAP)
            buf[total + lane] = 2;                         // sentinel ty2
    }
    return total;
}

// R19: fused mask+list build. One wave per pair: compute the 16 ballot words
// directly from inspk, distribute word w to lane w, write ffmask (still
// needed by fallback + slow paths) AND extract_cap the shared list in the
// same pass. Identical masks -> identical lists (bit-exact); deletes the
// snn_fflist dispatch + its 512KB ffmask re-read.
__global__ __launch_bounds__(256) void snn_ffboth(
    const float* __restrict__ inspk,
    unsigned long long* __restrict__ ffmask,
    int* __restrict__ fflist,
    int* __restrict__ fflist_n)
{
    const int lane = threadIdx.x & 63;
    const int wv   = threadIdx.x >> 6;
    const int w    = blockIdx.x * 4 + wv;      // 250 blocks x 4 waves = 1000
    for (int q = 0; q < 4; ++q) {
        const int p = w * 4 + q;               // pair index = t*8 + b
        const int t = p >> 3, b = p & 7;
        const size_t rowb = ((size_t)b * T_STEPS + t) * 16;
        unsigned long long mf = 0ULL;
#pragma unroll
        for (int widx = 0; widx < 16; ++widx) {
            const float v = inspk[(rowb + widx) * 64 + lane];
            const unsigned long long m = __ballot(v > 0.5f);
            if (lane == widx) mf = m;          // word widx -> lane widx
        }
        if (lane < 16) ffmask[rowb + lane] = mf;
        const int n = extract_cap(mf, fflist + (size_t)p * FFP_CAP, lane);
        if (lane == 0) fflist_n[p] = n;
    }
}

// Combined typed gather (recurrent): proven pipelined structure. Unchanged.
__device__ __forceinline__ void gather2(const int* __restrict__ lst, int npad,
                                        const float* __restrict__ base,
                                        float se, float si,
                                        float* oe, float* oi) {
#pragma clang fp contract(off)
    float ae = 0.0f, ai = 0.0f;
    const int4* lst4 = (const int4*)lst;
    for (int k = 0; k < npad; k += 64) {
        int4  eq[16];
        int   e[64];
        float w[64];
#pragma unroll
        for (int u = 0; u < 16; ++u) eq[u] = lst4[(k >> 2) + u];
#pragma unroll
        for (int u = 0; u < 16; ++u) {
            e[4 * u + 0] = eq[u].x; e[4 * u + 1] = eq[u].y;
            e[4 * u + 2] = eq[u].z; e[4 * u + 3] = eq[u].w;
        }
#pragma unroll
        for (int u = 0; u < 64; ++u) w[u] = base[(size_t)(e[u] >> 2) << 12];
#pragma unroll
        for (int u = 0; u < 64; ++u) {
            const int ty = e[u] & 3;
            const float sc = (ty == 0) ? se : ((ty == 1) ? si : 0.0f);
            const float p  = w[u] * sc;           // per-element product rounding = W_eff
            ae = (ty == 0) ? ae + p : ae;
            ai = (ty == 1) ? ai + p : ai;
        }
    }
    *oe = ae; *oi = ai;
}

// FF precompute v5 + R19 head-prefetch: staged-LDS Wff tile + shared lists,
// 1024 threads (4 waves/SIMD). The next pair's count + first 16 list entries
// are carried in registers across iterations, breaking the per-pair serial
// head (nf load ~300cy -> branch -> chunk0 load ~500cy) identified in R12.
// Chunks >= 1 stay dynamic (R17: static overfold costs more than it saves).
// Bit-exact: same entries, same ascending fold order; chunk0-from-registers
// holds identical values; sentinel slots give +0 adds; nf==0 folds nothing.
__global__ __launch_bounds__(1024) void snn_ffpre5(
    const unsigned long long* __restrict__ ffmask,
    const float* __restrict__ Wff,
    const float* __restrict__ sfff,
    const int*   __restrict__ ci,
    const int*   __restrict__ fflist,
    const int*   __restrict__ fflist_n,
    float*       __restrict__ ffdrive)
{
#pragma clang fp contract(off)
    const int tid = threadIdx.x;
    const int s   = blockIdx.x & 127;        // column slice [s*32, s*32+32)
    const int tbh = blockIdx.x >> 7;         // tb half: 0 or 1
    __shared__ float lwff[N_IN * FFP_STRIDE];   // 132 KB, stride-33 padded

    // stage Wff column-slice: 1024 threads, 32 rows in parallel, coalesced
    {
        const int j  = tid & 31;
        const int r0 = tid >> 5;             // 0..31
        for (int r = r0; r < N_IN; r += 32)
            lwff[r * FFP_STRIDE + j] = Wff[(size_t)r * N_NEU + (s << 5) + j];
    }
    __syncthreads();

    const int lane   = tid & 63;
    const int wv     = tid >> 6;             // 0..15
    const int j      = lane & 31;
    const int h      = lane >> 5;
    const int jg     = (s << 5) + j;
    const float sff  = sfff[ci[jg]];
    const int stream = (wv << 1) | h;        // 0..31 fold streams

    // prime the pipeline: count + first chunk of the first pair
    int  nfC = 0;
    int4 eqC[4];
    if (stream < 2000) {
        const int p0 = tbh * 2000 + stream;
        nfC = fflist_n[p0];
        const int4* l40 = (const int4*)(fflist + (size_t)p0 * FFP_CAP);
#pragma unroll
        for (int u = 0; u < 4; ++u) eqC[u] = l40[u];
    }

    for (int pl = stream; pl < 2000; pl += 32) {   // wave-uniform trip count
        const int p = tbh * 2000 + pl;

        // prefetch next pair's head (issues early; drains under this fold)
        const int pln = pl + 32;
        int  nfN = 0;
        int4 eqN[4] = {};
        if (pln < 2000) {
            const int pn = tbh * 2000 + pln;
            nfN = fflist_n[pn];
            const int4* l4n = (const int4*)(fflist + (size_t)pn * FFP_CAP);
#pragma unroll
            for (int u = 0; u < 4; ++u) eqN[u] = l4n[u];
        }

        float acc = 0.0f;
        if (nfC > FFP_CAP) {
            // exact slow path (P~1e-18 for this input): ascending bit-walk
            const int t = p >> 3, b = p & 7;
            const unsigned long long* mp =
                ffmask + ((size_t)b * T_STEPS + t) * 16;
            for (int w16 = 0; w16 < 16; ++w16) {
                unsigned long long mw = mp[w16];
                const int base = w16 << 6;
                while (mw) {
                    const int bit = __builtin_ctzll(mw); mw &= mw - 1ULL;
                    const float pr = lwff[(base + bit) * FFP_STRIDE + j] * sff;
                    acc += pr;
                }
            }
        } else if (nfC > 0) {
            // chunk 0 from registers (identical values to memory chunk 0;
            // slots nfC..15 are sentinels when nfC<16 -> sc=0)
            {
                int e[16];
#pragma unroll
                for (int u = 0; u < 4; ++u) {
                    e[4 * u + 0] = eqC[u].x; e[4 * u + 1] = eqC[u].y;
                    e[4 * u + 2] = eqC[u].z; e[4 * u + 3] = eqC[u].w;
                }
                float wf[16];
#pragma unroll
                for (int u = 0; u < 16; ++u)
                    wf[u] = lwff[(e[u] >> 2) * FFP_STRIDE + j];
#pragma unroll
                for (int u = 0; u < 16; ++u) {
                    const float sc = ((e[u] & 3) == 0) ? sff : 0.0f;
                    const float pr = wf[u] * sc;
                    acc += pr;               // ascending-i left fold
                }
            }
            const int nch = (nfC + 15) >> 4; // remaining 16-entry chunks
            const int4* l4 = (const int4*)(fflist + (size_t)p * FFP_CAP);
            for (int c = 1; c < nch; ++c) {
                int4 eq[4];
#pragma unroll
                for (int u = 0; u < 4; ++u) eq[u] = l4[c * 4 + u];
                int e[16];
#pragma unroll
                for (int u = 0; u < 4; ++u) {
                    e[4 * u + 0] = eq[u].x; e[4 * u + 1] = eq[u].y;
                    e[4 * u + 2] = eq[u].z; e[4 * u + 3] = eq[u].w;
                }
                float wf[16];
#pragma unroll
                for (int u = 0; u < 16; ++u)
                    wf[u] = lwff[(e[u] >> 2) * FFP_STRIDE + j];
#pragma unroll
                for (int u = 0; u < 16; ++u) {
                    const float sc = ((e[u] & 3) == 0) ? sff : 0.0f;
                    const float pr = wf[u] * sc;
                    acc += pr;               // ascending-i left fold
                }
            }
        }
        ffdrive[(size_t)p * N_NEU + jg] = acc;   // p == t*8+b == layout index

        nfC = nfN;
#pragma unroll
        for (int u = 0; u < 4; ++u) eqC[u] = eqN[u];
    }
}

// Old FF precompute (R6-proven, ~425us LLC-bound): workspace fallback only.
__global__ __launch_bounds__(64) void snn_ffpre(const unsigned long long* __restrict__ ffmask,
                                                const float* __restrict__ Wff,
                                                const float* __restrict__ sfff,
                                                const int*   __restrict__ ci,
                                                float*       __restrict__ ffdrive) {
#pragma clang fp contract(off)
    const int lane  = threadIdx.x;
    const int chunk = blockIdx.x & 63;
    const int tile  = blockIdx.x >> 6;     // 160 tiles of 25 (t,b) pairs
    const int i     = (chunk << 6) + lane;
    const float s_ff = sfff[ci[i]];
    __shared__ alignas(16) int lds_f[N_IN + 64];
    for (int p = tile * 25; p < tile * 25 + 25; ++p) {
        const int t = p >> 3, b = p & 7;
        const unsigned long long mf =
            (lane < 16) ? ffmask[((size_t)b * T_STEPS + t) * 16 + lane] : 0ULL;
        const int n = extract_pad(mf, ~0ULL, lds_f, lane);   // all ty0
        float fd, dummy;
        gather2(lds_f, (n + 63) & ~63, Wff + i, s_ff, 0.0f, &fd, &dummy);
        ffdrive[((size_t)t * B_SZ + b) * N_NEU + i] = fd;
    }
}

__global__ __launch_bounds__(256) void snn_run(
    const float* __restrict__ W,       // (N,N) row j = presyn
    const float* __restrict__ Wff,     // (NI,N)
    const float* __restrict__ sf,      // (2,2)
    const float* __restrict__ sfff,    // (1,2)
    const int*   __restrict__ ci,      // (N)
    float*       __restrict__ out,     // (B,T,N)
    const unsigned long long* __restrict__ ffmask,
    const unsigned long long* __restrict__ tmask_g,
    const float* __restrict__ ffdrive,
    int use_ffpre,
    unsigned long long* __restrict__ mb2)
{
#pragma clang fp contract(off)
    const int tid   = threadIdx.x;
    const int lane  = tid & 63;
    const int wv    = tid >> 6;
    const int bid   = blockIdx.x;
    // slice from bits {0,1,2,6}, batch from bits {3,4,5}
    const int slice = (((bid >> 6) & 1) << 3) | (bid & 7);
    const int b     = (bid >> 3) & 7;
    const int i     = (slice << 8) + (wv << 6) + lane;    // my post neuron
    const int c     = ci[i];

    const float s_exc = sf[c];
    const float s_inh = sf[2 + c];
    const float s_ff  = sfff[c];

    const unsigned long long my_tm = tmask_g[lane];

    // Per-wave private LDS regions: NO cross-wave sharing -> no barriers.
    __shared__ alignas(16) int lds_c[4][N_NEU + 64];
    __shared__ alignas(16) int lds_f[4][N_IN + 64];
    int* const my_ldsc = lds_c[wv];
    int* const my_ldsf = lds_f[wv];

    // mb2 layout (u64 units): [parity][batch][entry=(slice<<2)|wv][half]
    unsigned long long* const mbB = mb2 + (size_t)b * 128;

    float v = -70.0f, rf = 0.0f;
    float h0 = 0.0f, h1 = 0.0f, h2 = 0.0f, h3 = 0.0f;
    float g0 = 0.0f, g1 = 0.0f, g2 = 0.0f, g3 = 0.0f;

    const float aR0 = expf(-0.1f / 0.5f);
    const float aR1 = expf(-0.1f / 2.0f);
    const float aD0 = expf(-0.1f / 2.0f);
    const float aD1 = expf(-0.1f / 100.0f);
    const float aD2 = expf(-0.1f / 5.0f);
    const float kmem   = c ? (0.1f / 10.0f) : (0.1f / 20.0f);
    const float rsteps = c ? 10.0f : 20.0f;

    // warming base: this wave's 256B segment start within any W row
    const float* const wseg = W + (size_t)((slice << 8) + (wv << 6));

    for (int t = 0; t < T_STEPS; ++t) {
        // ffdrive issued BEFORE the poll: its ~600cy latency hides under
        // detection. asm keep-alive pins the load above the poll loop.
        float ffd = 0.0f;
        if (use_ffpre) {
            ffd = ffdrive[((size_t)t * B_SZ + b) * N_NEU + i];
            asm volatile("" :: "v"(ffd));
        }

        unsigned long long mw = 0ULL;
        if (t > 0) {
            // tagged single-hop poll: lane l owns entry l; parity dbuf; no
            // ABA (publish(t+2) requires every block past poll(t)).
            // HOT spin (R18, proven): retry rate self-limited by ~500cy RT.
            const unsigned int tg = (unsigned int)t;
            const unsigned long long* ep =
                mbB + (size_t)(t & 1) * 1024 + ((size_t)lane << 1);
            unsigned long long w0, w1;
            for (;;) {
                w0 = __hip_atomic_load(&ep[0], __ATOMIC_RELAXED,
                                       __HIP_MEMORY_SCOPE_AGENT);
                w1 = __hip_atomic_load(&ep[1], __ATOMIC_RELAXED,
                                       __HIP_MEMORY_SCOPE_AGENT);
                const bool ok = ((unsigned int)(w0 >> 32) == tg) &&
                                ((unsigned int)(w1 >> 32) == tg);
                if (__ballot(ok) == ~0ULL) break;
            }
            mw = (w0 & 0xFFFFFFFFULL) | ((w1 & 0xFFFFFFFFULL) << 32);
            asm volatile("" ::: "memory");   // keep LDS writes below poll
        }

        // ---- line warming: pull this step's W row-segments toward L1 while
        // the extract scan runs; real gather loads MSHR-merge.
        {
            unsigned long long mm = mw;
            float wacc = 0.0f;
            const size_t rowbase = (size_t)lane << 18;  // (lane*64)<<12 floats
            while (mm) {
                const int bit = __builtin_ctzll(mm); mm &= mm - 1ULL;
                const float* r = wseg + rowbase + ((size_t)bit << 12);
                wacc += r[0]; wacc += r[16]; wacc += r[32]; wacc += r[48];
            }
            asm volatile("" :: "v"(wacc));
        }

        // zero-skip: fully-silent network step -> no extract scan needed.
        int ne = 0;
        if (__ballot(mw != 0ULL) != 0ULL)
            ne = extract_pad(mw, my_tm, my_ldsc, lane);

        if (!use_ffpre) {
            const unsigned long long mf =
                (lane < 16) ? ffmask[((size_t)b * T_STEPS + t) * 16 + lane] : 0ULL;
            const int nf = extract_pad(mf, ~0ULL, my_ldsf, lane);
            float fd, dummy;
            gather2(my_ldsf, (nf + 63) & ~63, Wff + i, s_ff, 0.0f, &fd, &dummy);
            ffd = fd;
        }

        float exc, inh;
        gather2(my_ldsc, (ne + 63) & ~63, W + i, s_exc, s_inh, &exc, &inh);

        // ---- neuron update (identical fp op sequence to R0-R18: bit-exact) ----
        const float d0 = exc;
        const float d1 = 0.5f * exc;
        const float d2 = inh;
        const float d3 = ffd;

        h0 = fmaf(h0, aR0, d0);
        h1 = fmaf(h1, aR1, d1);
        h2 = fmaf(h2, aR0, d2);
        h3 = fmaf(h3, aR0, d3);
        g0 = fmaf(g0, aD0, (1.0f - aD0) * h0);
        g1 = fmaf(g1, aD1, (1.0f - aD1) * h1);
        g2 = fmaf(g2, aD2, (1.0f - aD2) * h2);
        g3 = fmaf(g3, aD0, (1.0f - aD0) * h3);

        const float p0 = g0 * (0.0f - v);
        const float p1 = g1 * (0.0f - v);
        const float p2 = g2 * (-80.0f - v);
        const float p3 = g3 * (0.0f - v);
        const float Isyn = ((p0 + p1) + p2) + p3;

        float vn = fmaf(kmem, (-70.0f - v) + Isyn / 10.0f, v);
        const bool refr = rf > 0.0f;
        if (refr) vn = -65.0f;
        const float sn = (!refr && (vn > -50.0f)) ? 1.0f : 0.0f;
        const bool spk = sn > 0.5f;

        // publish at the EARLIEST instant: right after the spike decision,
        // before v/rf bookkeeping and the out store. Fire-and-forget.
        const unsigned long long sm = __ballot(spk);
        if (lane == 0) {
            const unsigned long long tg =
                (unsigned long long)(unsigned int)(t + 1) << 32;
            unsigned long long* pp = mb2 + (size_t)((t + 1) & 1) * 1024
                                   + (size_t)b * 128
                                   + ((size_t)((slice << 2) | wv) << 1);
            __hip_atomic_store(&pp[0], tg | (sm & 0xFFFFFFFFULL),
                               __ATOMIC_RELAXED, __HIP_MEMORY_SCOPE_AGENT);
            __hip_atomic_store(&pp[1], tg | (sm >> 32),
                               __ATOMIC_RELAXED, __HIP_MEMORY_SCOPE_AGENT);
        }

        v  = spk ? -65.0f : vn;
        rf = spk ? rsteps : fmaxf(rf - 1.0f, 0.0f);
        out[((size_t)b * T_STEPS + t) * N_NEU + i] = sn;   // regular store
    }
}

extern "C" void kernel_launch(void* const* d_in, const int* in_sizes, int n_in,
                              void* d_out, int out_size, void* d_ws, size_t ws_size,
                              hipStream_t stream) {
    const float* inspk = (const float*)d_in[0];
    const float* W     = (const float*)d_in[1];
    const float* Wff   = (const float*)d_in[2];
    const float* sf    = (const float*)d_in[3];
    const float* sfff  = (const float*)d_in[4];
    const int*   ci    = (const int*)d_in[5];

    float* out = (float*)d_out;
    unsigned long long* tmask    = (unsigned long long*)((char*)d_ws + WS_TM_OFF);
    unsigned long long* mb2      = (unsigned long long*)((char*)d_ws + WS_MB_OFF);
    unsigned long long* ffmask   = (unsigned long long*)((char*)d_ws + WS_FFM_OFF);
    float*              ffdrive  = (float*)((char*)d_ws + WS_FFD_OFF);
    int*                fflist_n = (int*)((char*)d_ws + WS_FLN_OFF);
    int*                fflist   = (int*)((char*)d_ws + WS_FL_OFF);

    const int use_fl    = (ws_size >= WS_NEED_FL) ? 1 : 0;
    const int use_ffpre = (ws_size >= WS_NEED_FFD) ? 1 : 0;

    snn_init<<<64, 64, 0, stream>>>(ci, tmask, mb2);
    if (use_fl) {
        snn_ffboth<<<250, 256, 0, stream>>>(inspk, ffmask, fflist, fflist_n);
        snn_ffpre5<<<256, 1024, 0, stream>>>(ffmask, Wff, sfff, ci,
                                             fflist, fflist_n, ffdrive);
    } else {
        snn_ffmask<<<1000, 256, 0, stream>>>(inspk, ffmask);
        if (use_ffpre)
            snn_ffpre<<<160 * 64, 64, 0, stream>>>(ffmask, Wff, sfff, ci, ffdrive);
    }
    snn_run<<<NBLK, 256, 0, stream>>>(W, Wff, sf, sfff, ci, out,
                                      ffmask, tmask, ffdrive, use_ffpre, mb2);
}